// Round 7
// baseline (1427.477 us; speedup 1.0000x reference)
//
#include <hip/hip_runtime.h>
#include <hip/hip_bf16.h>
#include <cstdint>
#include <cstddef>

#define NB 16
#define NN 8192
#define NS 512
#define NK 32
#define NG (NB*NS)          // 8192 groups
#define GPB 4               // groups per pass-block
#define NBLK (NG/GPB)       // 2048
#define NPOSI 262144        // NG*NK positions

// float64 squared distance, numpy order ((dx*dx + dy*dy) + dz*dz), no contraction.
__device__ __forceinline__ double sq3d(double dx, double dy, double dz){
#pragma clang fp contract(off)
  const double a = dx*dx;
  const double b = dy*dy;
  const double c = dz*dz;
  return (a + b) + c;
}

// One DPP combine step on an exact (f64 value, index) argmax pair.
// Order: max value; ties -> min index (numpy first-argmax).
template<int CTRL, int RMASK>
__device__ __forceinline__ void dpp_cmb(double& v, int& idx){
  const long long bb = __double_as_longlong(v);
  const int vlo = (int)(unsigned)(bb & 0xffffffffll);
  const int vhi = (int)(bb >> 32);
  const int olo = __builtin_amdgcn_update_dpp(vlo, vlo, CTRL, RMASK, 0xf, false);
  const int ohi = __builtin_amdgcn_update_dpp(vhi, vhi, CTRL, RMASK, 0xf, false);
  const int oid = __builtin_amdgcn_update_dpp(idx, idx, CTRL, RMASK, 0xf, false);
  const double ov = __longlong_as_double(((long long)ohi << 32) | (unsigned)olo);
  if (ov > v || (ov == v && oid < idx)){ v = ov; idx = oid; }
}
// 64-lane argmax; result valid in lane 63 (masked-off lanes keep own value = no-op combine)
__device__ __forceinline__ void wave_argmax63(double& v, int& idx){
  dpp_cmb<0xB1,0xf>(v,idx);    // quad_perm xor1
  dpp_cmb<0x4E,0xf>(v,idx);    // quad_perm xor2
  dpp_cmb<0x141,0xf>(v,idx);   // row_half_mirror
  dpp_cmb<0x140,0xf>(v,idx);   // row_mirror -> all lanes have row-of-16 max
  dpp_cmb<0x142,0xa>(v,idx);   // row_bcast15 into rows 1,3
  dpp_cmb<0x143,0xc>(v,idx);   // row_bcast31 into rows 2,3 -> lane63 complete
}
// argmax over groups of 16 lanes (entries replicated x4) -> ALL lanes get result
__device__ __forceinline__ void grp16_argmax(double& v, int& idx){
  dpp_cmb<0xB1,0xf>(v,idx);
  dpp_cmb<0x4E,0xf>(v,idx);
  dpp_cmb<0x141,0xf>(v,idx);
  dpp_cmb<0x140,0xf>(v,idx);
}

// ---------------- FPS: f32 screen + exact f64 state; 1 barrier, 0 atomics/iter ----------------
__global__ __launch_bounds__(1024) void k_fps(const float* __restrict__ xyz,
                                              float* __restrict__ newxyz){
  const int b = blockIdx.x;
  const int t = threadIdx.x;
  const float* __restrict__ X = xyz + (size_t)b*NN*3;
  float px[8], py[8], pz[8], thr[8];
  double dd[8];
#pragma unroll
  for (int j=0;j<8;++j){
    const int p = t + 1024*j;
    px[j]=X[p*3+0]; py[j]=X[p*3+1]; pz[j]=X[p*3+2];
    dd[j]=1e10;
    thr[j]=fmaf(1e10f, 0x1p-19f, 1e10f);
  }
  double tmax = 1e10;
  int    tidx = t;              // all-equal dd -> first index within thread is j=0 -> t

  __shared__ double sWv[2][16];
  __shared__ int    sWi[2][16];
  __shared__ int    sSel[NS];
  const int wid = t >> 6;

  int f = 0;
  for (int i=0;i<NS;++i){
    if (t == 0) sSel[i] = f;
    if (i == NS-1) break;                       // last argmax unused
    const int par = i & 1;

    // ---- f32 screen (+rare exact f64 update), incremental (tmax,tidx) ----
    const float* __restrict__ P = X + 3*(size_t)f;   // uniform addr -> L2
    const float cx32=P[0], cy32=P[1], cz32=P[2];
    float d32v[8];
    bool anyu = false;
#pragma unroll
    for (int j=0;j<8;++j){
      const float ax=px[j]-cx32, ay=py[j]-cy32, az=pz[j]-cz32;
      d32v[j] = fmaf(az, az, fmaf(ay, ay, ax*ax));   // screen only: any rounding
      anyu = anyu | (d32v[j] <= thr[j]);
    }
    if (__builtin_expect(anyu, 0)){
      const double cx=(double)cx32, cy=(double)cy32, cz=(double)cz32;
#pragma unroll
      for (int j=0;j<8;++j){
        if (d32v[j] <= thr[j]){
          const double d = sq3d((double)px[j]-cx, (double)py[j]-cy, (double)pz[j]-cz);
          const double nd = fmin(dd[j], d);
          dd[j] = nd;
          const float nd32 = (float)nd;
          thr[j] = fmaf(nd32, 0x1p-19f, nd32);
        }
      }
      double tm = -1.0; int ti = 0x7fffffff;
#pragma unroll
      for (int j=7;j>=0;--j)
        if (dd[j] >= tm){ tm = dd[j]; ti = t + 1024*j; }   // desc scan keeps min j on ties
      tmax = tm; tidx = ti;
    }

    // ---- exact in-wave pair argmax -> lane63 plain write ----
    double v = tmax; int ix = tidx;
    wave_argmax63(v, ix);
    if ((t & 63) == 63){ sWv[par][wid] = v; sWi[par][wid] = ix; }
    __syncthreads();   // the ONLY barrier per iteration (parity dbuf covers reuse)

    // ---- cross-wave: 16 entries replicated x4, DPP reduce, uniform result ----
    double gv = sWv[par][t & 15];
    int    gi = sWi[par][t & 15];
    grp16_argmax(gv, gi);
    f = __builtin_amdgcn_readfirstlane(gi);
  }
  __syncthreads();
  // flush centroids once
  if (t < NS){
    const int id = sSel[t];
    float* o = newxyz + ((size_t)b*NS + t)*3;
    o[0]=X[id*3+0]; o[1]=X[id*3+1]; o[2]=X[id*3+2];
  }
}

// ---------------- Ball query: one wave per centroid, f32 screen + f64 band ----------------
__global__ __launch_bounds__(256) void k_ball(const float* __restrict__ xyz,
                                              const float* __restrict__ newxyz,
                                              int* __restrict__ idx){
  const int w = (blockIdx.x << 2) + (threadIdx.x >> 6);  // group id = b*NS+s
  const int lane = threadIdx.x & 63;
  const int b = w >> 9;
  const float* __restrict__ C = newxyz + (size_t)w*3;
  const float cxf=C[0], cyf=C[1], czf=C[2];
  const double cx=(double)cxf, cy=(double)cyf, cz=(double)czf;
  const float* __restrict__ X = xyz + (size_t)b*NN*3;
  int* __restrict__ out = idx + (size_t)w*NK;
  const double R2 = 0.2*0.2;                   // f64: 0.04000000000000000083...
  const float r2lo = 0.04f*(1.0f - 0x1p-16f);  // certain-in  below
  const float r2hi = 0.04f*(1.0f + 0x1p-16f);  // certain-out above
  int count = 0, first = 0;
  for (int base=0; base<NN && count<NK; base+=64){
    const int p = base + lane;
    const float ax=X[p*3+0]-cxf, ay=X[p*3+1]-cyf, az=X[p*3+2]-czf;
    const float d32 = fmaf(az, az, fmaf(ay, ay, ax*ax));
    bool q;
    if (d32 <= r2lo)      q = true;
    else if (d32 > r2hi)  q = false;
    else {                                     // rare band: exact f64 decision
      const double d = sq3d((double)X[p*3+0]-cx, (double)X[p*3+1]-cy, (double)X[p*3+2]-cz);
      q = !(d > R2);
    }
    const unsigned long long m = __ballot(q);
    if (q){
      const int pos = count + __popcll(m & ((1ull<<lane)-1ull));
      if (pos < NK) out[pos] = p;
    }
    if (count == 0 && m) first = base + __builtin_ctzll(m);
    count += __popcll(m);
  }
  if (lane >= count && lane < NK) out[lane] = first;   // pad with first index
}

// ---------------- per-block stats (+optional group min/max) reduction ----------------
__device__ __forceinline__ void stats_reduce(
    float v[4][8], float* __restrict__ sRed, int t, int tp, int tc, int blk,
    int chtot, int choff, bool domm,
    float* __restrict__ pS, float* __restrict__ pQ,
    float* __restrict__ mxp, float* __restrict__ mnp)
{
  __syncthreads();   // sRed overlays sX0/sW0/sV — ensure all prior reads done
  float S=0.f, Q=0.f;
  for (int m=0;m<4;++m){
#pragma unroll
    for (int i=0;i<8;++i) sRed[tp*68 + tc*8 + i] = v[m][i];
    __syncthreads();
    if (t < 64){
      float mxv = -3.402823466e38f, mnv = 3.402823466e38f;
#pragma unroll
      for (int j=0;j<32;++j){
        const float x = sRed[j*68 + t];
        S += x; Q += x*x;
        mxv = fmaxf(mxv,x); mnv = fminf(mnv,x);
      }
      if (domm){
        const int gg = blk*GPB + m;
        mxp[(size_t)gg*128 + choff + t] = mxv;
        mnp[(size_t)gg*128 + choff + t] = mnv;
      }
    }
    __syncthreads();
  }
  if (t < 64){
    pS[(size_t)blk*chtot + choff + t] = S;
    pQ[(size_t)blk*chtot + choff + t] = Q;
  }
}

// 64-deep inner product accumulate: v[m][i] += sX[pos_m][k]*sW[ch_i][k]
__device__ __forceinline__ void mm64(const float* __restrict__ sXl,
                                     const float* __restrict__ sWl,
                                     int tp, int tc, float v[4][8]){
#pragma unroll 4
  for (int k=0;k<64;++k){
    float xv[4], wv[8];
#pragma unroll
    for (int m=0;m<4;++m) xv[m] = sXl[(tp+32*m)*65 + k];
#pragma unroll
    for (int i=0;i<8;++i) wv[i] = sWl[(tc*8+i)*65 + k];
#pragma unroll
    for (int m=0;m<4;++m)
#pragma unroll
      for (int i=0;i<8;++i) v[m][i] += xv[m]*wv[i];
  }
}

// ---------------- MLP pass: recompute chain to layer DEPTH, emit stats ----------------
template<int DEPTH>
__global__ __launch_bounds__(256) void k_pass(
    const float* __restrict__ xyz, const float* __restrict__ points,
    const float* __restrict__ newxyz, const int* __restrict__ idx,
    const float* __restrict__ w0, const float* __restrict__ b0,
    const float* __restrict__ w1, const float* __restrict__ b1,
    const float* __restrict__ w2, const float* __restrict__ b2,
    const float* __restrict__ ac,
    float* __restrict__ pS, float* __restrict__ pQ,
    float* __restrict__ mxp, float* __restrict__ mnp)
{
  __shared__ float smem[(DEPTH>=1) ? 14784 : 2304];
  float* sX0 = smem;
  float* sW0 = smem + 1024;
  float* sV  = smem + 1600;
  float* sRed= smem;            // overlay
  float* sB2 = smem + 2176;
  float* sW1 = smem + 2304;
  float* sX  = smem + 6464;

  const int t = threadIdx.x;
  const int blk = blockIdx.x;
  const int tc = t & 7, tp = t >> 3;

  // stage weights / params
  for (int i=t;i<384;i+=256) sW0[(i/6)*9 + (i%6)] = w0[i];
  if (t < 64) sV[t] = b0[t];
  if constexpr (DEPTH >= 1){
    if (t < 64){ sV[64+t]=ac[t]; sV[128+t]=ac[64+t]; sV[192+t]=b1[t]; }
    for (int i=t;i<4096;i+=256) sW1[(i>>6)*65 + (i&63)] = w1[i];
  }
  if constexpr (DEPTH == 2){
    if (t < 64){ sV[256+t]=ac[128+t]; sV[320+t]=ac[192+t]; }
    if (t < 128) sB2[t] = b2[t];
  }

  // gather -> x0 (6 ch): [gxyz - centroid, gpts]
  {
    const int pos = t & 127;
    const int gg = blk*GPB + (pos >> 5);
    const int b  = gg >> 9;
    const int id = idx[gg*NK + (pos & 31)];
    if (t < 128){
      const float* __restrict__ P = xyz + ((size_t)b*NN + id)*3;
      const float* __restrict__ C = newxyz + (size_t)gg*3;
      sX0[pos*8+0] = P[0]-C[0];
      sX0[pos*8+1] = P[1]-C[1];
      sX0[pos*8+2] = P[2]-C[2];
    } else {
      const float* __restrict__ P = points + ((size_t)b*NN + id)*3;
      sX0[pos*8+3] = P[0];
      sX0[pos*8+4] = P[1];
      sX0[pos*8+5] = P[2];
    }
  }
  __syncthreads();

  // y0 = W0 x0 + b0   (thread: 4 positions x 8 channels)
  float v[4][8];
#pragma unroll
  for (int m=0;m<4;++m){
    const int pos = tp + 32*m;
    float xr[6];
#pragma unroll
    for (int c=0;c<6;++c) xr[c] = sX0[pos*8+c];
#pragma unroll
    for (int i=0;i<8;++i){
      const int ch = tc*8+i;
      float acc = sV[ch];
#pragma unroll
      for (int c=0;c<6;++c) acc += sW0[ch*9+c]*xr[c];
      v[m][i] = acc;
    }
  }

  if constexpr (DEPTH == 0){
    stats_reduce(v, sRed, t, tp, tc, blk, 64, 0, false, pS, pQ, mxp, mnp);
    return;
  } else {
    // x1 = relu(a0*y0 + c0)
#pragma unroll
    for (int m=0;m<4;++m){
      const int pos = tp + 32*m;
#pragma unroll
      for (int i=0;i<8;++i){
        const int ch = tc*8+i;
        sX[pos*65+ch] = fmaxf(sV[64+ch]*v[m][i] + sV[128+ch], 0.f);
      }
    }
    __syncthreads();
    // y1 = W1 x1 + b1
#pragma unroll
    for (int m=0;m<4;++m)
#pragma unroll
      for (int i=0;i<8;++i) v[m][i] = sV[192 + tc*8 + i];
    mm64(sX, sW1, tp, tc, v);

    if constexpr (DEPTH == 1){
      stats_reduce(v, sRed, t, tp, tc, blk, 64, 0, false, pS, pQ, mxp, mnp);
      return;
    } else {
      __syncthreads();
      // x2 = relu(a1*y1 + c1), overwrite sX
#pragma unroll
      for (int m=0;m<4;++m){
        const int pos = tp + 32*m;
#pragma unroll
        for (int i=0;i<8;++i){
          const int ch = tc*8+i;
          sX[pos*65+ch] = fmaxf(sV[256+ch]*v[m][i] + sV[320+ch], 0.f);
        }
      }
      __syncthreads();
      // y2 = W2 x2 + b2 in two 64-channel chunks (W2 chunk reuses sW1 space)
      for (int o=0;o<2;++o){
        for (int i=t;i<4096;i+=256) sW1[(i>>6)*65 + (i&63)] = w2[o*4096 + i];
        __syncthreads();
#pragma unroll
        for (int m=0;m<4;++m)
#pragma unroll
          for (int i=0;i<8;++i) v[m][i] = sB2[o*64 + tc*8 + i];
        mm64(sX, sW1, tp, tc, v);
        stats_reduce(v, sRed, t, tp, tc, blk, 128, o*64, true, pS, pQ, mxp, mnp);
      }
      return;
    }
  }
}

// ---------------- derive BN affine a,c: segmented 1024-thread reduce ----------------
__global__ __launch_bounds__(1024) void k_stats(const float* __restrict__ pS, const float* __restrict__ pQ,
                                                const float* __restrict__ g, const float* __restrict__ beta,
                                                float* __restrict__ a, float* __restrict__ c, int CH){
  __shared__ float sS[1024], sQ[1024];
  const int t = threadIdx.x;
  const int ch = t & (CH-1);
  const int seg = t / CH;
  const int SEG = 1024 / CH;          // 16 (CH=64) or 8 (CH=128)
  const int rows = NBLK / SEG;        // 128 or 256
  float S=0.f, Q=0.f;
  const int j0 = seg*rows;
#pragma unroll 4
  for (int r=0;r<rows;++r){
    const size_t o = (size_t)(j0+r)*CH + ch;
    S += pS[o]; Q += pQ[o];
  }
  sS[t]=S; sQ[t]=Q;
  __syncthreads();
  if (t < CH){
    float aS=0.f, aQ=0.f;
    for (int s2=0;s2<SEG;++s2){ aS += sS[s2*CH+ch]; aQ += sQ[s2*CH+ch]; }
    const float mean = aS * (1.f/(float)NPOSI);
    const float var  = fmaxf(aQ * (1.f/(float)NPOSI) - mean*mean, 0.f);
    const float av = g[ch] * rsqrtf(var + 1e-5f);
    a[ch] = av;
    c[ch] = beta[ch] - mean*av;
  }
}

// ---------------- final: BN+ReLU applied to pooled value ----------------
__global__ __launch_bounds__(256) void k_final(const float* __restrict__ mxp, const float* __restrict__ mnp,
                                               const float* __restrict__ a, const float* __restrict__ c,
                                               float* __restrict__ out){
  const int i = blockIdx.x*256 + threadIdx.x;
  const int ch = i & 127;
  const float av = a[ch], cv = c[ch];
  const float vv = (av >= 0.f) ? mxp[i] : mnp[i];   // relu∘affine is monotone
  out[i] = fmaxf(av*vv + cv, 0.f);
}

extern "C" void kernel_launch(void* const* d_in, const int* in_sizes, int n_in,
                              void* d_out, int out_size, void* d_ws, size_t ws_size,
                              hipStream_t stream){
  (void)in_sizes; (void)n_in; (void)out_size;
  const float* xyz    = (const float*)d_in[0];
  const float* points = (const float*)d_in[1];
  const float* w0 = (const float*)d_in[2];
  const float* b0 = (const float*)d_in[3];
  const float* g0 = (const float*)d_in[4];
  const float* be0= (const float*)d_in[5];
  const float* w1 = (const float*)d_in[6];
  const float* b1 = (const float*)d_in[7];
  const float* g1 = (const float*)d_in[8];
  const float* be1= (const float*)d_in[9];
  const float* w2 = (const float*)d_in[10];
  const float* b2 = (const float*)d_in[11];
  const float* g2 = (const float*)d_in[12];
  const float* be2= (const float*)d_in[13];

  float* out_newxyz = (float*)d_out;
  float* out_newpts = out_newxyz + (size_t)NB*NS*3;

  char* ws = (char*)d_ws;
  int*   idx = (int*)ws;                              // 1 MiB
  float* ac  = (float*)(ws + (1u<<20));               // 512 floats (a0,c0,a1,c1,a2,c2)
  float* pS  = (float*)(ws + (1u<<20) + 4096);        // 2048*128 f
  float* pQ  = pS + (size_t)NBLK*128;                 // 2048*128 f
  float* mxp = pQ + (size_t)NBLK*128;                 // 8192*128 f
  float* mnp = mxp + (size_t)NG*128;                  // 8192*128 f
  const size_t need = (1u<<20) + 4096 + (size_t)2*NBLK*128*4 + (size_t)2*NG*128*4;
  if (ws_size < need) return;  // ~11.5 MiB required

  k_fps <<<NB, 1024, 0, stream>>>(xyz, out_newxyz);
  k_ball<<<NG/4, 256, 0, stream>>>(xyz, out_newxyz, idx);

  k_pass<0><<<NBLK,256,0,stream>>>(xyz,points,out_newxyz,idx,w0,b0,w1,b1,w2,b2,ac,pS,pQ,mxp,mnp);
  k_stats<<<1,1024,0,stream>>>(pS,pQ,g0,be0, ac+0,   ac+64,  64);
  k_pass<1><<<NBLK,256,0,stream>>>(xyz,points,out_newxyz,idx,w0,b0,w1,b1,w2,b2,ac,pS,pQ,mxp,mnp);
  k_stats<<<1,1024,0,stream>>>(pS,pQ,g1,be1, ac+128, ac+192, 64);
  k_pass<2><<<NBLK,256,0,stream>>>(xyz,points,out_newxyz,idx,w0,b0,w1,b1,w2,b2,ac,pS,pQ,mxp,mnp);
  k_stats<<<1,1024,0,stream>>>(pS,pQ,g2,be2, ac+256, ac+384, 128);
  k_final<<<(NG*128)/256,256,0,stream>>>(mxp,mnp,ac+256,ac+384,out_newpts);
}

// Round 8
// 1256.023 us; speedup vs baseline: 1.1365x; 1.1365x over previous
//
#include <hip/hip_runtime.h>
#include <hip/hip_bf16.h>
#include <cstdint>
#include <cstddef>

#define NB 16
#define NN 8192
#define NS 512
#define NK 32
#define NG (NB*NS)          // 8192 groups
#define GPB 4               // groups per pass-block
#define NBLK (NG/GPB)       // 2048
#define NPOSI 262144        // NG*NK positions

typedef float v2f __attribute__((ext_vector_type(2)));

// float64 squared distance, numpy order ((dx*dx + dy*dy) + dz*dz), no contraction.
__device__ __forceinline__ double sq3d(double dx, double dy, double dz){
#pragma clang fp contract(off)
  const double a = dx*dx;
  const double b = dy*dy;
  const double c = dz*dz;
  return (a + b) + c;
}

// one DPP-max step on a u32 (nonneg-float bitpattern: u32 order == float order)
template<int CTRL>
__device__ __forceinline__ unsigned dpp_umax_step(unsigned v){
  const unsigned o = (unsigned)__builtin_amdgcn_update_dpp(0, (int)v, CTRL, 0xf, 0xf, false);
  return v > o ? v : o;
}
// full-wave (64-lane) max; result valid in lane 63
__device__ __forceinline__ unsigned wave_umax63(unsigned v){
  v = dpp_umax_step<0xB1>(v);    // quad_perm xor1
  v = dpp_umax_step<0x4E>(v);    // quad_perm xor2
  v = dpp_umax_step<0x141>(v);   // row_half_mirror
  v = dpp_umax_step<0x140>(v);   // row_mirror
  v = dpp_umax_step<0x142>(v);   // row_bcast15
  v = dpp_umax_step<0x143>(v);   // row_bcast31 -> lane63 complete
  return v;
}

// ---------------- FPS: packed-f32 screen + exact f64 state ----------------
// Invariants: dd[] is the exact numpy-f64 min-distance array; (tmax,tidx) is the
// exact per-thread argmax pair with tmax == dd[tidx>>10]; thr = dd32*(1+2^-19)
// is a conservative screen bound (if d64 < dd64 then d32 <= thr; proof round 4).
__global__ __launch_bounds__(1024,4) void k_fps(const float* __restrict__ xyz,
                                                float* __restrict__ newxyz){
  const int b = blockIdx.x;
  const int t = threadIdx.x;
  const float* __restrict__ X = xyz + (size_t)b*NN*3;
  v2f px[4], py[4], pz[4], thr2[4];
  double dd[8];
#pragma unroll
  for (int j=0;j<8;++j){
    const int p = t + 1024*j;
    px[j>>1][j&1]=X[p*3+0]; py[j>>1][j&1]=X[p*3+1]; pz[j>>1][j&1]=X[p*3+2];
    dd[j]=1e10;
    thr2[j>>1][j&1]=fmaf(1e10f, 0x1p-19f, 1e10f);
  }
  double tmax = 1e10;
  float  tmax32 = 1e10f;
  int    tidx = t;              // all-equal dd -> first index within thread is j=0 -> t

  __shared__ __align__(16) unsigned sM32[2][16];
  __shared__ unsigned long long sMax64[2];
  __shared__ int sIdx[2];
  __shared__ int sSel[NS];
  if (t < 2){ sMax64[t]=0ull; sIdx[t]=0x7fffffff; }
  __syncthreads();

  int f = 0;
  for (int i=0;i<NS;++i){
    if (t == 0) sSel[i] = f;
    if (i == NS-1) break;                       // last argmax unused
    const int par = i & 1;

    // ---- packed f32 screen ----
    const float* __restrict__ P = X + 3*(size_t)f;   // uniform addr -> L2
    const float cx=P[0], cy=P[1], cz=P[2];
    const v2f c2x={cx,cx}, c2y={cy,cy}, c2z={cz,cz};
    v2f e2[4];
    float mmin = 1e30f;
#pragma unroll
    for (int q=0;q<4;++q){
      const v2f ax = px[q]-c2x, ay = py[q]-c2y, az = pz[q]-c2z;
      const v2f d  = ax*ax + ay*ay + az*az;          // pk ops; any rounding (screen only)
      const v2f e  = d - thr2[q];
      e2[q] = e;
      mmin = fminf(mmin, fminf(e[0], e[1]));
    }

    // ---- rare exact f64 path ----
    if (__builtin_expect(mmin <= 0.f, 0)){
      const double cxd=(double)cx, cyd=(double)cy, czd=(double)cz;
      const int tj = tidx >> 10;
      bool needscan = false;
#pragma unroll
      for (int j=0;j<8;++j){
        if (e2[j>>1][j&1] <= 0.f){
          const double d64 = sq3d((double)px[j>>1][j&1]-cxd,
                                  (double)py[j>>1][j&1]-cyd,
                                  (double)pz[j>>1][j&1]-czd);
          const double nd = fmin(dd[j], d64);
          dd[j] = nd;
          const float nd32 = (float)nd;
          thr2[j>>1][j&1] = fmaf(nd32, 0x1p-19f, nd32);
          needscan |= (j == tj);                 // only max-slot updates can move tmax
        }
      }
      if (needscan){
        double tm=-1.0; int ti=0;
#pragma unroll
        for (int j=7;j>=0;--j)
          if (dd[j] >= tm){ tm=dd[j]; ti=t+1024*j; }   // desc scan keeps min j on ties
        tmax=tm; tidx=ti; tmax32=(float)tm;
      }
    }

    // ---- phase 1: f32 wave max, plain per-wave store ----
    const unsigned vb = wave_umax63(__float_as_uint(tmax32));
    if ((t & 63) == 63) sM32[par][t>>6] = vb;
    __syncthreads();   // barrier 1

    // all threads: block M32 from 16 slots (broadcast reads, no conflicts)
    const uint4* p4 = (const uint4*)sM32[par];
    const uint4 A=p4[0], Bq=p4[1], Cq=p4[2], Dq=p4[3];
    unsigned m32 = A.x;
    m32 = m32>A.y?m32:A.y;  m32 = m32>A.z?m32:A.z;  m32 = m32>A.w?m32:A.w;
    m32 = m32>Bq.x?m32:Bq.x; m32 = m32>Bq.y?m32:Bq.y; m32 = m32>Bq.z?m32:Bq.z; m32 = m32>Bq.w?m32:Bq.w;
    m32 = m32>Cq.x?m32:Cq.x; m32 = m32>Cq.y?m32:Cq.y; m32 = m32>Cq.z?m32:Cq.z; m32 = m32>Cq.w?m32:Cq.w;
    m32 = m32>Dq.x?m32:Dq.x; m32 = m32>Dq.y?m32:Dq.y; m32 = m32>Dq.z?m32:Dq.z; m32 = m32>Dq.w?m32:Dq.w;

    // ---- phase 2: exact f64 max among f32 candidates (typically 1 thread) ----
    const bool cand = (__float_as_uint(tmax32) == m32);
    if (cand) atomicMax(&sMax64[par], (unsigned long long)__double_as_longlong(tmax));
    __syncthreads();   // barrier 2

    // ---- phase 3: first-index among exact-value ties ----
    if (cand && (unsigned long long)__double_as_longlong(tmax) == sMax64[par])
      atomicMin(&sIdx[par], tidx);
    if (t == 0){ sMax64[par^1]=0ull; sIdx[par^1]=0x7fffffff; }
    __syncthreads();   // barrier 3
    f = sIdx[par];
  }
  __syncthreads();
  // flush centroids once
  if (t < NS){
    const int id = sSel[t];
    float* o = newxyz + ((size_t)b*NS + t)*3;
    o[0]=X[id*3+0]; o[1]=X[id*3+1]; o[2]=X[id*3+2];
  }
}

// ---------------- Ball query: one wave per centroid, f32 screen + f64 band ----------------
__global__ __launch_bounds__(256) void k_ball(const float* __restrict__ xyz,
                                              const float* __restrict__ newxyz,
                                              int* __restrict__ idx){
  const int w = (blockIdx.x << 2) + (threadIdx.x >> 6);  // group id = b*NS+s
  const int lane = threadIdx.x & 63;
  const int b = w >> 9;
  const float* __restrict__ C = newxyz + (size_t)w*3;
  const float cxf=C[0], cyf=C[1], czf=C[2];
  const double cx=(double)cxf, cy=(double)cyf, cz=(double)czf;
  const float* __restrict__ X = xyz + (size_t)b*NN*3;
  int* __restrict__ out = idx + (size_t)w*NK;
  const double R2 = 0.2*0.2;                   // f64: 0.04000000000000000083...
  const float r2lo = 0.04f*(1.0f - 0x1p-16f);  // certain-in  below
  const float r2hi = 0.04f*(1.0f + 0x1p-16f);  // certain-out above
  int count = 0, first = 0;
  for (int base=0; base<NN && count<NK; base+=64){
    const int p = base + lane;
    const float ax=X[p*3+0]-cxf, ay=X[p*3+1]-cyf, az=X[p*3+2]-czf;
    const float d32 = fmaf(az, az, fmaf(ay, ay, ax*ax));
    bool q;
    if (d32 <= r2lo)      q = true;
    else if (d32 > r2hi)  q = false;
    else {                                     // rare band: exact f64 decision
      const double d = sq3d((double)X[p*3+0]-cx, (double)X[p*3+1]-cy, (double)X[p*3+2]-cz);
      q = !(d > R2);
    }
    const unsigned long long m = __ballot(q);
    if (q){
      const int pos = count + __popcll(m & ((1ull<<lane)-1ull));
      if (pos < NK) out[pos] = p;
    }
    if (count == 0 && m) first = base + __builtin_ctzll(m);
    count += __popcll(m);
  }
  if (lane >= count && lane < NK) out[lane] = first;   // pad with first index
}

// ---------------- per-block stats (+optional group min/max) reduction ----------------
__device__ __forceinline__ void stats_reduce(
    float v[4][8], float* __restrict__ sRed, int t, int tp, int tc, int blk,
    int chtot, int choff, bool domm,
    float* __restrict__ pS, float* __restrict__ pQ,
    float* __restrict__ mxp, float* __restrict__ mnp)
{
  __syncthreads();   // sRed overlays sX0/sW0/sV — ensure all prior reads done
  float S=0.f, Q=0.f;
  for (int m=0;m<4;++m){
#pragma unroll
    for (int i=0;i<8;++i) sRed[tp*68 + tc*8 + i] = v[m][i];
    __syncthreads();
    if (t < 64){
      float mxv = -3.402823466e38f, mnv = 3.402823466e38f;
#pragma unroll
      for (int j=0;j<32;++j){
        const float x = sRed[j*68 + t];
        S += x; Q += x*x;
        mxv = fmaxf(mxv,x); mnv = fminf(mnv,x);
      }
      if (domm){
        const int gg = blk*GPB + m;
        mxp[(size_t)gg*128 + choff + t] = mxv;
        mnp[(size_t)gg*128 + choff + t] = mnv;
      }
    }
    __syncthreads();
  }
  if (t < 64){
    pS[(size_t)blk*chtot + choff + t] = S;
    pQ[(size_t)blk*chtot + choff + t] = Q;
  }
}

// 64-deep inner product accumulate: v[m][i] += sX[pos_m][k]*sW[ch_i][k]
__device__ __forceinline__ void mm64(const float* __restrict__ sXl,
                                     const float* __restrict__ sWl,
                                     int tp, int tc, float v[4][8]){
#pragma unroll 4
  for (int k=0;k<64;++k){
    float xv[4], wv[8];
#pragma unroll
    for (int m=0;m<4;++m) xv[m] = sXl[(tp+32*m)*65 + k];
#pragma unroll
    for (int i=0;i<8;++i) wv[i] = sWl[(tc*8+i)*65 + k];
#pragma unroll
    for (int m=0;m<4;++m)
#pragma unroll
      for (int i=0;i<8;++i) v[m][i] += xv[m]*wv[i];
  }
}

// ---------------- MLP pass: recompute chain to layer DEPTH, emit stats ----------------
template<int DEPTH>
__global__ __launch_bounds__(256) void k_pass(
    const float* __restrict__ xyz, const float* __restrict__ points,
    const float* __restrict__ newxyz, const int* __restrict__ idx,
    const float* __restrict__ w0, const float* __restrict__ b0,
    const float* __restrict__ w1, const float* __restrict__ b1,
    const float* __restrict__ w2, const float* __restrict__ b2,
    const float* __restrict__ ac,
    float* __restrict__ pS, float* __restrict__ pQ,
    float* __restrict__ mxp, float* __restrict__ mnp)
{
  __shared__ float smem[(DEPTH>=1) ? 14784 : 2304];
  float* sX0 = smem;
  float* sW0 = smem + 1024;
  float* sV  = smem + 1600;
  float* sRed= smem;            // overlay
  float* sB2 = smem + 2176;
  float* sW1 = smem + 2304;
  float* sX  = smem + 6464;

  const int t = threadIdx.x;
  const int blk = blockIdx.x;
  const int tc = t & 7, tp = t >> 3;

  // stage weights / params
  for (int i=t;i<384;i+=256) sW0[(i/6)*9 + (i%6)] = w0[i];
  if (t < 64) sV[t] = b0[t];
  if constexpr (DEPTH >= 1){
    if (t < 64){ sV[64+t]=ac[t]; sV[128+t]=ac[64+t]; sV[192+t]=b1[t]; }
    for (int i=t;i<4096;i+=256) sW1[(i>>6)*65 + (i&63)] = w1[i];
  }
  if constexpr (DEPTH == 2){
    if (t < 64){ sV[256+t]=ac[128+t]; sV[320+t]=ac[192+t]; }
    if (t < 128) sB2[t] = b2[t];
  }

  // gather -> x0 (6 ch): [gxyz - centroid, gpts]
  {
    const int pos = t & 127;
    const int gg = blk*GPB + (pos >> 5);
    const int b  = gg >> 9;
    const int id = idx[gg*NK + (pos & 31)];
    if (t < 128){
      const float* __restrict__ P = xyz + ((size_t)b*NN + id)*3;
      const float* __restrict__ C = newxyz + (size_t)gg*3;
      sX0[pos*8+0] = P[0]-C[0];
      sX0[pos*8+1] = P[1]-C[1];
      sX0[pos*8+2] = P[2]-C[2];
    } else {
      const float* __restrict__ P = points + ((size_t)b*NN + id)*3;
      sX0[pos*8+3] = P[0];
      sX0[pos*8+4] = P[1];
      sX0[pos*8+5] = P[2];
    }
  }
  __syncthreads();

  // y0 = W0 x0 + b0   (thread: 4 positions x 8 channels)
  float v[4][8];
#pragma unroll
  for (int m=0;m<4;++m){
    const int pos = tp + 32*m;
    float xr[6];
#pragma unroll
    for (int c=0;c<6;++c) xr[c] = sX0[pos*8+c];
#pragma unroll
    for (int i=0;i<8;++i){
      const int ch = tc*8+i;
      float acc = sV[ch];
#pragma unroll
      for (int c=0;c<6;++c) acc += sW0[ch*9+c]*xr[c];
      v[m][i] = acc;
    }
  }

  if constexpr (DEPTH == 0){
    stats_reduce(v, sRed, t, tp, tc, blk, 64, 0, false, pS, pQ, mxp, mnp);
    return;
  } else {
    // x1 = relu(a0*y0 + c0)
#pragma unroll
    for (int m=0;m<4;++m){
      const int pos = tp + 32*m;
#pragma unroll
      for (int i=0;i<8;++i){
        const int ch = tc*8+i;
        sX[pos*65+ch] = fmaxf(sV[64+ch]*v[m][i] + sV[128+ch], 0.f);
      }
    }
    __syncthreads();
    // y1 = W1 x1 + b1
#pragma unroll
    for (int m=0;m<4;++m)
#pragma unroll
      for (int i=0;i<8;++i) v[m][i] = sV[192 + tc*8 + i];
    mm64(sX, sW1, tp, tc, v);

    if constexpr (DEPTH == 1){
      stats_reduce(v, sRed, t, tp, tc, blk, 64, 0, false, pS, pQ, mxp, mnp);
      return;
    } else {
      __syncthreads();
      // x2 = relu(a1*y1 + c1), overwrite sX
#pragma unroll
      for (int m=0;m<4;++m){
        const int pos = tp + 32*m;
#pragma unroll
        for (int i=0;i<8;++i){
          const int ch = tc*8+i;
          sX[pos*65+ch] = fmaxf(sV[256+ch]*v[m][i] + sV[320+ch], 0.f);
        }
      }
      __syncthreads();
      // y2 = W2 x2 + b2 in two 64-channel chunks (W2 chunk reuses sW1 space)
      for (int o=0;o<2;++o){
        for (int i=t;i<4096;i+=256) sW1[(i>>6)*65 + (i&63)] = w2[o*4096 + i];
        __syncthreads();
#pragma unroll
        for (int m=0;m<4;++m)
#pragma unroll
          for (int i=0;i<8;++i) v[m][i] = sB2[o*64 + tc*8 + i];
        mm64(sX, sW1, tp, tc, v);
        stats_reduce(v, sRed, t, tp, tc, blk, 128, o*64, true, pS, pQ, mxp, mnp);
      }
      return;
    }
  }
}

// ---------------- derive BN affine a,c: segmented 1024-thread reduce ----------------
__global__ __launch_bounds__(1024) void k_stats(const float* __restrict__ pS, const float* __restrict__ pQ,
                                                const float* __restrict__ g, const float* __restrict__ beta,
                                                float* __restrict__ a, float* __restrict__ c, int CH){
  __shared__ float sS[1024], sQ[1024];
  const int t = threadIdx.x;
  const int ch = t & (CH-1);
  const int seg = t / CH;
  const int SEG = 1024 / CH;          // 16 (CH=64) or 8 (CH=128)
  const int rows = NBLK / SEG;        // 128 or 256
  float S=0.f, Q=0.f;
  const int j0 = seg*rows;
#pragma unroll 4
  for (int r=0;r<rows;++r){
    const size_t o = (size_t)(j0+r)*CH + ch;
    S += pS[o]; Q += pQ[o];
  }
  sS[t]=S; sQ[t]=Q;
  __syncthreads();
  if (t < CH){
    float aS=0.f, aQ=0.f;
    for (int s2=0;s2<SEG;++s2){ aS += sS[s2*CH+ch]; aQ += sQ[s2*CH+ch]; }
    const float mean = aS * (1.f/(float)NPOSI);
    const float var  = fmaxf(aQ * (1.f/(float)NPOSI) - mean*mean, 0.f);
    const float av = g[ch] * rsqrtf(var + 1e-5f);
    a[ch] = av;
    c[ch] = beta[ch] - mean*av;
  }
}

// ---------------- final: BN+ReLU applied to pooled value ----------------
__global__ __launch_bounds__(256) void k_final(const float* __restrict__ mxp, const float* __restrict__ mnp,
                                               const float* __restrict__ a, const float* __restrict__ c,
                                               float* __restrict__ out){
  const int i = blockIdx.x*256 + threadIdx.x;
  const int ch = i & 127;
  const float av = a[ch], cv = c[ch];
  const float vv = (av >= 0.f) ? mxp[i] : mnp[i];   // relu∘affine is monotone
  out[i] = fmaxf(av*vv + cv, 0.f);
}

extern "C" void kernel_launch(void* const* d_in, const int* in_sizes, int n_in,
                              void* d_out, int out_size, void* d_ws, size_t ws_size,
                              hipStream_t stream){
  (void)in_sizes; (void)n_in; (void)out_size;
  const float* xyz    = (const float*)d_in[0];
  const float* points = (const float*)d_in[1];
  const float* w0 = (const float*)d_in[2];
  const float* b0 = (const float*)d_in[3];
  const float* g0 = (const float*)d_in[4];
  const float* be0= (const float*)d_in[5];
  const float* w1 = (const float*)d_in[6];
  const float* b1 = (const float*)d_in[7];
  const float* g1 = (const float*)d_in[8];
  const float* be1= (const float*)d_in[9];
  const float* w2 = (const float*)d_in[10];
  const float* b2 = (const float*)d_in[11];
  const float* g2 = (const float*)d_in[12];
  const float* be2= (const float*)d_in[13];

  float* out_newxyz = (float*)d_out;
  float* out_newpts = out_newxyz + (size_t)NB*NS*3;

  char* ws = (char*)d_ws;
  int*   idx = (int*)ws;                              // 1 MiB
  float* ac  = (float*)(ws + (1u<<20));               // 512 floats (a0,c0,a1,c1,a2,c2)
  float* pS  = (float*)(ws + (1u<<20) + 4096);        // 2048*128 f
  float* pQ  = pS + (size_t)NBLK*128;                 // 2048*128 f
  float* mxp = pQ + (size_t)NBLK*128;                 // 8192*128 f
  float* mnp = mxp + (size_t)NG*128;                  // 8192*128 f
  const size_t need = (1u<<20) + 4096 + (size_t)2*NBLK*128*4 + (size_t)2*NG*128*4;
  if (ws_size < need) return;  // ~11.5 MiB required

  k_fps <<<NB, 1024, 0, stream>>>(xyz, out_newxyz);
  k_ball<<<NG/4, 256, 0, stream>>>(xyz, out_newxyz, idx);

  k_pass<0><<<NBLK,256,0,stream>>>(xyz,points,out_newxyz,idx,w0,b0,w1,b1,w2,b2,ac,pS,pQ,mxp,mnp);
  k_stats<<<1,1024,0,stream>>>(pS,pQ,g0,be0, ac+0,   ac+64,  64);
  k_pass<1><<<NBLK,256,0,stream>>>(xyz,points,out_newxyz,idx,w0,b0,w1,b1,w2,b2,ac,pS,pQ,mxp,mnp);
  k_stats<<<1,1024,0,stream>>>(pS,pQ,g1,be1, ac+128, ac+192, 64);
  k_pass<2><<<NBLK,256,0,stream>>>(xyz,points,out_newxyz,idx,w0,b0,w1,b1,w2,b2,ac,pS,pQ,mxp,mnp);
  k_stats<<<1,1024,0,stream>>>(pS,pQ,g2,be2, ac+256, ac+384, 128);
  k_final<<<(NG*128)/256,256,0,stream>>>(mxp,mnp,ac+256,ac+384,out_newpts);
}